// Round 7
// baseline (504.632 us; speedup 1.0000x reference)
//
#include <hip/hip_runtime.h>
#include <math.h>

#define D_MODEL 1024
#define NHEAD   16
#define HDIM    64
#define SEQ     2048
#define BATCH   4
#define NROWS   (BATCH*SEQ)   // 8192

// Q pre-scale: 1/sqrt(64) * log2(e), so attention can use exp2 directly.
#define QSCALE 0.1803368801111204f

using bf16x8 = __attribute__((ext_vector_type(8))) short;
using bf16x4 = __attribute__((ext_vector_type(4))) short;
using f32x4  = __attribute__((ext_vector_type(4))) float;

__device__ __forceinline__ unsigned short f2bf(float f) {
    unsigned u = __float_as_uint(f);
    u += 0x7fffu + ((u >> 16) & 1u);
    return (unsigned short)(u >> 16);
}
__device__ __forceinline__ float bf2f(unsigned short h) {
    unsigned u = ((unsigned)h) << 16;
    return __uint_as_float(u);
}
// 2^x via v_exp_f32 (gfx950 hw exp is base-2). __exp2f does not exist in HIP.
__device__ __forceinline__ float fast_exp2(float x) {
    return __builtin_amdgcn_exp2f(x);
}

#define ASYNC_COPY16(g, l) \
    __builtin_amdgcn_global_load_lds((__attribute__((address_space(1))) const void*)(g), \
                                     (__attribute__((address_space(3))) void*)(l), 16, 0, 0)

// ---------------- LayerNorm (LN1): one block per row of 1024 --------------------
__global__ __launch_bounds__(256) void ln_kernel(const float* __restrict__ x,
                                                 const float* __restrict__ g,
                                                 const float* __restrict__ b,
                                                 unsigned short* __restrict__ out) {
    const int row = blockIdx.x;
    const int tid = threadIdx.x;
    const float4* x4 = (const float4*)(x + (size_t)row * D_MODEL);
    float4 v = x4[tid];
    float s  = v.x + v.y + v.z + v.w;
    float sq = v.x*v.x + v.y*v.y + v.z*v.z + v.w*v.w;
    #pragma unroll
    for (int off = 32; off >= 1; off >>= 1) {
        s  += __shfl_down(s,  off, 64);
        sq += __shfl_down(sq, off, 64);
    }
    __shared__ float rs[4], rq[4];
    const int wave = tid >> 6;
    if ((tid & 63) == 0) { rs[wave] = s; rq[wave] = sq; }
    __syncthreads();
    const float tot  = rs[0] + rs[1] + rs[2] + rs[3];
    const float totq = rq[0] + rq[1] + rq[2] + rq[3];
    const float mu   = tot * (1.0f / D_MODEL);
    const float var  = totq * (1.0f / D_MODEL) - mu * mu;
    const float rstd = rsqrtf(var + 1e-5f);
    const float4 gv = ((const float4*)g)[tid];
    const float4 bv = ((const float4*)b)[tid];
    unsigned short* o = out + (size_t)row * D_MODEL + tid * 4;
    o[0] = f2bf((v.x - mu) * rstd * gv.x + bv.x);
    o[1] = f2bf((v.y - mu) * rstd * gv.y + bv.y);
    o[2] = f2bf((v.z - mu) * rstd * gv.z + bv.z);
    o[3] = f2bf((v.w - mu) * rstd * gv.w + bv.w);
}

// ------------- Weight transpose+convert: w[K][N] f32 -> wt[N][K] bf16 -----------
__global__ __launch_bounds__(256) void wt_kernel(const float* __restrict__ w,
                                                 unsigned short* __restrict__ wt,
                                                 int K, int N) {
    __shared__ float tile[32][33];
    const int n0 = blockIdx.x * 32, k0 = blockIdx.y * 32;
    const int tx = threadIdx.x & 31, ty = threadIdx.x >> 5;
    #pragma unroll
    for (int j = 0; j < 4; ++j)
        tile[ty + j * 8][tx] = w[(size_t)(k0 + ty + j * 8) * N + n0 + tx];
    __syncthreads();
    #pragma unroll
    for (int j = 0; j < 4; ++j)
        wt[(size_t)(n0 + ty + j * 8) * K + k0 + tx] = f2bf(tile[tx][ty + j * 8]);
}

// ------------- GEMM 256x128, BK=64 (grid: x=m, y=n, [z=split]) ------------------
// 4 waves 2x2: wave covers 128 rows x 64 cols = 8x4 MFMAs x 2 k-halves.
// 48 KiB LDS -> 2-3 blocks/CU. Used for w_o and proj (split-K, MODE 1).
template<int MODE>
__global__ __launch_bounds__(256, 2) void gemm_big(const unsigned short* __restrict__ A,
                                                   const unsigned short* __restrict__ Bt,
                                                   const float* __restrict__ bias,
                                                   unsigned short* __restrict__ outp,
                                                   unsigned short* __restrict__ vt_out,
                                                   int M, int N, int K, int Kslice) {
    __shared__ __align__(16) unsigned short As[256 * 64];   // 32 KiB
    __shared__ __align__(16) unsigned short Bs[128 * 64];   // 16 KiB

    const int tid  = threadIdx.x;
    const int lane = tid & 63;
    const int wave = __builtin_amdgcn_readfirstlane(tid >> 6);
    const int quad = lane >> 4, l16 = lane & 15;
    const int wm = wave >> 1, wn = wave & 1;
    const int m0 = blockIdx.x * 256, n0 = blockIdx.y * 128;

    int kbeg = 0, klen = K;
    if (MODE == 1) {
        kbeg = blockIdx.z * Kslice;
        klen = (blockIdx.z == (int)gridDim.z - 1) ? (K - kbeg) : Kslice;
    }

    f32x4 acc[8][4] = {};

    const int rr  = tid >> 3;                 // 0..31
    const int p   = tid & 7;
    const int gch = (p ^ (rr & 7)) * 8;       // swizzled global chunk (elements)

    const unsigned short* Ag[8];
    const unsigned short* Bg[4];
    #pragma unroll
    for (int i = 0; i < 8; ++i)
        Ag[i] = A + (size_t)(m0 + i * 32 + rr) * K + gch + kbeg;
    #pragma unroll
    for (int i = 0; i < 4; ++i)
        Bg[i] = Bt + (size_t)(n0 + i * 32 + rr) * K + gch + kbeg;

    const int pc = (quad ^ (l16 & 7)) * 8;

    for (int kb = 0; kb < klen; kb += 64) {
        #pragma unroll
        for (int i = 0; i < 8; ++i)
            ASYNC_COPY16(Ag[i] + kb, As + i * 2048 + tid * 8);
        #pragma unroll
        for (int i = 0; i < 4; ++i)
            ASYNC_COPY16(Bg[i] + kb, Bs + i * 2048 + tid * 8);
        __syncthreads();

        #pragma unroll
        for (int half = 0; half < 2; ++half) {
            const int off = half ? (pc ^ 32) : pc;
            bf16x8 b[4];
            #pragma unroll
            for (int j = 0; j < 4; ++j)
                b[j] = *(const bf16x8*)&Bs[(wn * 64 + j * 16 + l16) * 64 + off];
            #pragma unroll
            for (int i = 0; i < 8; ++i) {
                bf16x8 a = *(const bf16x8*)&As[(wm * 128 + i * 16 + l16) * 64 + off];
                #pragma unroll
                for (int j = 0; j < 4; ++j)
                    acc[i][j] = __builtin_amdgcn_mfma_f32_16x16x32_bf16(a, b[j], acc[i][j], 0, 0, 0);
            }
        }
        __syncthreads();
    }

    if (MODE == 1) {
        unsigned short* outb = outp + (size_t)blockIdx.z * M * N;
        #pragma unroll
        for (int i = 0; i < 8; ++i)
          #pragma unroll
          for (int j = 0; j < 4; ++j)
            #pragma unroll
            for (int r = 0; r < 4; ++r) {
                const int row = m0 + wm * 128 + i * 16 + quad * 4 + r;
                const int col = n0 + wn * 64 + j * 16 + l16;
                outb[(size_t)row * N + col] = f2bf(acc[i][j][r]);
            }
    }
    (void)bias; (void)vt_out;
}

// ------------- GEMM 256x256, BK=64, 8 waves (2x4), 2-barrier --------------------
// Verified structure (R4, passed): loads/thread 12->8, B staged once per 256
// cols, LDS 64 KiB -> 2 blocks/CU. Per-wave work identical to gemm_big.
// MODE 0: bias + gelu (fc). MODE 2: qkv dual-out (Q prescaled by QSCALE,
// V stored transposed); 256-col tile never straddles the 1024/2048 boundaries.
template<int MODE>
__global__ __launch_bounds__(512, 2) void gemm256(const unsigned short* __restrict__ A,
                                                  const unsigned short* __restrict__ Bt,
                                                  const float* __restrict__ bias,
                                                  unsigned short* __restrict__ outp,
                                                  unsigned short* __restrict__ vt_out,
                                                  int M, int N, int K) {
    __shared__ __align__(16) unsigned short As[256 * 64];   // 32 KiB
    __shared__ __align__(16) unsigned short Bs[256 * 64];   // 32 KiB

    const int tid  = threadIdx.x;
    const int lane = tid & 63;
    const int wave = __builtin_amdgcn_readfirstlane(tid >> 6);
    const int quad = lane >> 4, l16 = lane & 15;
    const int wm = wave >> 2, wn = wave & 3;
    const int m0 = blockIdx.x * 256, n0 = blockIdx.y * 256;

    f32x4 acc[8][4] = {};

    const int rr  = tid >> 3;                 // 0..63
    const int p   = tid & 7;
    const int gch = (p ^ (rr & 7)) * 8;       // swizzled global chunk (elements)

    const unsigned short* Ag[4];
    const unsigned short* Bg[4];
    #pragma unroll
    for (int i = 0; i < 4; ++i) {
        Ag[i] = A  + (size_t)(m0 + i * 64 + rr) * K + gch;
        Bg[i] = Bt + (size_t)(n0 + i * 64 + rr) * K + gch;
    }

    const int pc = (quad ^ (l16 & 7)) * 8;

    for (int kb = 0; kb < K; kb += 64) {
        #pragma unroll
        for (int i = 0; i < 4; ++i)
            ASYNC_COPY16(Ag[i] + kb, As + i * 4096 + tid * 8);
        #pragma unroll
        for (int i = 0; i < 4; ++i)
            ASYNC_COPY16(Bg[i] + kb, Bs + i * 4096 + tid * 8);
        __syncthreads();

        #pragma unroll
        for (int half = 0; half < 2; ++half) {
            const int off = half ? (pc ^ 32) : pc;
            bf16x8 b[4];
            #pragma unroll
            for (int j = 0; j < 4; ++j)
                b[j] = *(const bf16x8*)&Bs[(wn * 64 + j * 16 + l16) * 64 + off];
            #pragma unroll
            for (int i = 0; i < 8; ++i) {
                bf16x8 a = *(const bf16x8*)&As[(wm * 128 + i * 16 + l16) * 64 + off];
                #pragma unroll
                for (int j = 0; j < 4; ++j)
                    acc[i][j] = __builtin_amdgcn_mfma_f32_16x16x32_bf16(a, b[j], acc[i][j], 0, 0, 0);
            }
        }
        __syncthreads();
    }

    if (MODE == 0) {
        #pragma unroll
        for (int i = 0; i < 8; ++i)
          #pragma unroll
          for (int j = 0; j < 4; ++j)
            #pragma unroll
            for (int r = 0; r < 4; ++r) {
                const int row = m0 + wm * 128 + i * 16 + quad * 4 + r;
                const int col = n0 + wn * 64 + j * 16 + l16;
                float v = acc[i][j][r] + bias[col];
                const float u = 0.7978845608028654f * (v + 0.044715f * v * v * v);
                const float e = __expf(2.0f * u);
                v = 0.5f * v * (2.0f - 2.0f / (e + 1.0f));
                outp[(size_t)row * N + col] = f2bf(v);
            }
    } else {
        if (n0 < 2048) {
            const float sc = (n0 < 1024) ? QSCALE : 1.0f;
            #pragma unroll
            for (int i = 0; i < 8; ++i)
              #pragma unroll
              for (int j = 0; j < 4; ++j)
                #pragma unroll
                for (int r = 0; r < 4; ++r) {
                    const int row = m0 + wm * 128 + i * 16 + quad * 4 + r;
                    const int col = n0 + wn * 64 + j * 16 + l16;
                    outp[(size_t)row * 2048 + col] = f2bf(acc[i][j][r] * sc);
                }
        } else {
            #pragma unroll
            for (int i = 0; i < 8; ++i)
              #pragma unroll
              for (int j = 0; j < 4; ++j) {
                    const int dv  = n0 - 2048 + wn * 64 + j * 16 + l16;
                    const int tok = m0 + wm * 128 + i * 16 + quad * 4;
                    ushort4 pk;
                    pk.x = f2bf(acc[i][j][0]); pk.y = f2bf(acc[i][j][1]);
                    pk.z = f2bf(acc[i][j][2]); pk.w = f2bf(acc[i][j][3]);
                    *(ushort4*)(vt_out + (size_t)dv * NROWS + tok) = pk;
                }
        }
    }
}

// ------- fused w_o reduce: res1 = x + p0..p{NP-1} -> out(f32); LN2 -> lnout -----
template<int NP>
__global__ __launch_bounds__(256) void reduce_wo_ln2(const float* __restrict__ x,
                                                     const unsigned short* __restrict__ pw,
                                                     const float* __restrict__ g,
                                                     const float* __restrict__ bb,
                                                     float* __restrict__ out,
                                                     unsigned short* __restrict__ lnout) {
    const int row = blockIdx.x;
    const int tid = threadIdx.x;
    const size_t base = (size_t)row * D_MODEL + tid * 4;
    const size_t stride = (size_t)NROWS * D_MODEL;
    float4 v = *(const float4*)(x + base);
    #pragma unroll
    for (int z = 0; z < NP; ++z) {
        ushort4 a = *(const ushort4*)(pw + z * stride + base);
        v.x += bf2f(a.x); v.y += bf2f(a.y); v.z += bf2f(a.z); v.w += bf2f(a.w);
    }
    *(float4*)(out + base) = v;

    float s  = v.x + v.y + v.z + v.w;
    float sq = v.x*v.x + v.y*v.y + v.z*v.z + v.w*v.w;
    #pragma unroll
    for (int off = 32; off >= 1; off >>= 1) {
        s  += __shfl_down(s,  off, 64);
        sq += __shfl_down(sq, off, 64);
    }
    __shared__ float rs[4], rq[4];
    const int wave = tid >> 6;
    if ((tid & 63) == 0) { rs[wave] = s; rq[wave] = sq; }
    __syncthreads();
    const float tot  = rs[0] + rs[1] + rs[2] + rs[3];
    const float totq = rq[0] + rq[1] + rq[2] + rq[3];
    const float mu   = tot * (1.0f / D_MODEL);
    const float var  = totq * (1.0f / D_MODEL) - mu * mu;
    const float rstd = rsqrtf(var + 1e-5f);
    const float4 gv = ((const float4*)g)[tid];
    const float4 bv = ((const float4*)bb)[tid];
    unsigned short* o = lnout + (size_t)row * D_MODEL + tid * 4;
    o[0] = f2bf((v.x - mu) * rstd * gv.x + bv.x);
    o[1] = f2bf((v.y - mu) * rstd * gv.y + bv.y);
    o[2] = f2bf((v.z - mu) * rstd * gv.z + bv.z);
    o[3] = f2bf((v.w - mu) * rstd * gv.w + bv.w);
}

// ------------- proj split-K reduce: out += bias + p0..p{NP-1} -------------------
template<int NP>
__global__ __launch_bounds__(256) void reduce_kernel(float* __restrict__ out,
                                                     const unsigned short* __restrict__ pp,
                                                     const float* __restrict__ bias) {
    const int row = blockIdx.x;
    const int c0 = threadIdx.x * 4;
    const size_t base = (size_t)row * D_MODEL + c0;
    const size_t stride = (size_t)NROWS * D_MODEL;
    float4 o = *(float4*)(out + base);
    const float4 bs = *(const float4*)(bias + c0);
    o.x += bs.x; o.y += bs.y; o.z += bs.z; o.w += bs.w;
    #pragma unroll
    for (int z = 0; z < NP; ++z) {
        ushort4 a = *(const ushort4*)(pp + z * stride + base);
        o.x += bf2f(a.x); o.y += bf2f(a.y); o.z += bf2f(a.z); o.w += bf2f(a.w);
    }
    *(float4*)(out + base) = o;
}

// ---------------- Flash attention, causal, balanced (paired 128-q tiles) --------
// Double-buffered K/V (prefetch kt+1 at top of kt; vmcnt(0) at tile end only).
// Mid-tile barrier removed (Ps rows intra-wave). exp2 path (Q prescaled by
// log2e at QKV). s_setprio(1) around MFMA clusters (guide m191: attn-positive).
__global__ __launch_bounds__(256) void attn_kernel(const unsigned short* __restrict__ qk,
                                                   const unsigned short* __restrict__ VT,
                                                   unsigned short* __restrict__ y) {
    __shared__ __align__(16) unsigned short Qs[128 * 64];      // 16 KiB
    __shared__ __align__(16) unsigned short Ks[2][64 * 64];    // 16 KiB
    __shared__ __align__(16) unsigned short Vs[2][64 * 64];    // 16 KiB
    __shared__ __align__(16) unsigned short Ones[16 * 64];     //  2 KiB
    __shared__ __align__(16) unsigned short Ps[128 * 68];      // 17 KiB

    const int tid  = threadIdx.x;
    const int lane = tid & 63, w = tid >> 6;
    const int quad = lane >> 4, l16 = lane & 15;
    const int s7   = l16 & 7;
    const int pc0  = (quad ^ s7) * 8;
    const int pc1  = ((quad + 4) ^ s7) * 8;
    const int srow = tid >> 3, sp = tid & 7;
    const int sc   = sp ^ (srow & 7);

    const int pairidx = blockIdx.x;
    const int bh = blockIdx.y;
    const int b = bh >> 4, h = bh & 15;
    const size_t rowbase = (size_t)b * SEQ;
    const unsigned short* Qbase = qk + h * 64;
    const unsigned short* Kbase = qk + 1024 + h * 64;
    const unsigned short* Vbase = VT + (size_t)(h * 64) * NROWS + b * SEQ;

    const unsigned short* Kg0 = Kbase + (rowbase + srow) * 2048 + sc * 8;
    const unsigned short* Kg1 = Kg0 + (size_t)32 * 2048;
    const unsigned short* Vg0 = Vbase + (size_t)srow * NROWS + sc * 8;
    const unsigned short* Vg1 = Vg0 + (size_t)32 * NROWS;

    #pragma unroll
    for (int e = 0; e < 4; ++e) {
        const int off = tid * 4 + e;
        Ones[off] = (off < 64) ? (unsigned short)0x3F80 : (unsigned short)0;
    }

    for (int phase = 0; phase < 2; ++phase) {
        const int Q = phase ? pairidx : (15 - pairidx);
        const int nkt = 2 * Q + 2;
        const int qg0 = Q * 128;

        #pragma unroll
        for (int i = 0; i < 4; ++i)
            ASYNC_COPY16(Qbase + (rowbase + qg0 + i * 32 + srow) * 2048 + sc * 8,
                         (char*)Qs + i * 4096 + tid * 16);
        ASYNC_COPY16(Kg0, (char*)&Ks[0][0] + tid * 16);
        ASYNC_COPY16(Kg1, (char*)&Ks[0][0] + 4096 + tid * 16);
        ASYNC_COPY16(Vg0, (char*)&Vs[0][0] + tid * 16);
        ASYNC_COPY16(Vg1, (char*)&Vs[0][0] + 4096 + tid * 16);
        __syncthreads();

        bf16x8 aq[2][2];
        #pragma unroll
        for (int sub = 0; sub < 2; ++sub) {
            const int qrow = sub * 64 + w * 16 + l16;
            aq[sub][0] = *(const bf16x8*)&Qs[qrow * 64 + pc0];
            aq[sub][1] = *(const bf16x8*)&Qs[qrow * 64 + pc1];
        }

        f32x4 o[2][5] = {};

        for (int kt = 0; kt < nkt; ++kt) {
            const int buf = kt & 1;
            if (kt + 1 < nkt) {
                const size_t koK = (size_t)(kt + 1) * 64 * 2048;
                const size_t koV = (size_t)(kt + 1) * 64;
                ASYNC_COPY16(Kg0 + koK, (char*)&Ks[buf ^ 1][0] + tid * 16);
                ASYNC_COPY16(Kg1 + koK, (char*)&Ks[buf ^ 1][0] + 4096 + tid * 16);
                ASYNC_COPY16(Vg0 + koV, (char*)&Vs[buf ^ 1][0] + tid * 16);
                ASYNC_COPY16(Vg1 + koV, (char*)&Vs[buf ^ 1][0] + 4096 + tid * 16);
            }

            bf16x8 bk[4][2];
            #pragma unroll
            for (int cb = 0; cb < 4; ++cb) {
                const int krow = cb * 16 + l16;
                bk[cb][0] = *(const bf16x8*)&Ks[buf][krow * 64 + pc0];
                bk[cb][1] = *(const bf16x8*)&Ks[buf][krow * 64 + pc1];
            }

            #pragma unroll
            for (int sub = 0; sub < 2; ++sub) {
                if (kt > 2 * Q + sub) continue;
                f32x4 s[4] = {};
                __builtin_amdgcn_s_setprio(1);
                #pragma unroll
                for (int cb = 0; cb < 4; ++cb) {
                    s[cb] = __builtin_amdgcn_mfma_f32_16x16x32_bf16(aq[sub][0], bk[cb][0], s[cb], 0, 0, 0);
                    s[cb] = __builtin_amdgcn_mfma_f32_16x16x32_bf16(aq[sub][1], bk[cb][1], s[cb], 0, 0, 0);
                }
                __builtin_amdgcn_s_setprio(0);
                const int prow0 = sub * 64 + w * 16 + quad * 4;
                if (kt == 2 * Q + sub) {
                    const int qg = qg0 + prow0;
                    const int kg = kt * 64 + l16;
                    #pragma unroll
                    for (int cb = 0; cb < 4; ++cb)
                        #pragma unroll
                        for (int r = 0; r < 4; ++r) {
                            const float e = fast_exp2(s[cb][r]);
                            const float pv = (kg + cb * 16 > qg + r) ? 0.0f : e;
                            Ps[(prow0 + r) * 68 + cb * 16 + l16] = f2bf(pv);
                        }
                } else {
                    #pragma unroll
                    for (int cb = 0; cb < 4; ++cb)
                        #pragma unroll
                        for (int r = 0; r < 4; ++r)
                            Ps[(prow0 + r) * 68 + cb * 16 + l16] = f2bf(fast_exp2(s[cb][r]));
                }
            }
            asm volatile("s_waitcnt lgkmcnt(0)" ::: "memory");

            bf16x8 bv[5][2];
            #pragma unroll
            for (int db = 0; db < 4; ++db) {
                const int vrow = db * 16 + l16;
                bv[db][0] = *(const bf16x8*)&Vs[buf][vrow * 64 + pc0];
                bv[db][1] = *(const bf16x8*)&Vs[buf][vrow * 64 + pc1];
            }
            bv[4][0] = *(const bf16x8*)&Ones[l16 * 64 + pc0];
            bv[4][1] = *(const bf16x8*)&Ones[l16 * 64 + pc1];

            #pragma unroll
            for (int sub = 0; sub < 2; ++sub) {
                if (kt > 2 * Q + sub) continue;
                const unsigned short* pb = &Ps[(sub * 64 + w * 16 + l16) * 68];
                bf16x8 ap0, ap1;
                *(bf16x4*)&ap0       = *(const bf16x4*)(pb + quad * 8);
                *((bf16x4*)&ap0 + 1) = *(const bf16x4*)(pb + quad * 8 + 4);
                *(bf16x4*)&ap1       = *(const bf16x4*)(pb + 32 + quad * 8);
                *((bf16x4*)&ap1 + 1) = *(const bf16x4*)(pb + 32 + quad * 8 + 4);
                __builtin_amdgcn_s_setprio(1);
                #pragma unroll
                for (int db = 0; db < 5; ++db) {
                    o[sub][db] = __builtin_amdgcn_mfma_f32_16x16x32_bf16(ap0, bv[db][0], o[sub][db], 0, 0, 0);
                    o[sub][db] = __builtin_amdgcn_mfma_f32_16x16x32_bf16(ap1, bv[db][1], o[sub][db], 0, 0, 0);
                }
                __builtin_amdgcn_s_setprio(0);
            }
            asm volatile("s_waitcnt vmcnt(0)" ::: "memory");
            __syncthreads();
        }

        #pragma unroll
        for (int sub = 0; sub < 2; ++sub)
            #pragma unroll
            for (int r = 0; r < 4; ++r) {
                const float lsum = __shfl(o[sub][4][r], lane & 48);
                const float rinv = 1.0f / lsum;
                const int trow = qg0 + sub * 64 + w * 16 + quad * 4 + r;
                unsigned short* yp = y + (rowbase + trow) * (size_t)D_MODEL + h * 64 + l16;
                #pragma unroll
                for (int db = 0; db < 4; ++db)
                    yp[db * 16] = f2bf(o[sub][db][r] * rinv);
            }
    }
}

extern "C" void kernel_launch(void* const* d_in, const int* in_sizes, int n_in,
                              void* d_out, int out_size, void* d_ws, size_t ws_size,
                              hipStream_t stream) {
    (void)in_sizes; (void)n_in; (void)out_size; (void)ws_size;
    const float* x      = (const float*)d_in[0];
    const float* w_attn = (const float*)d_in[1];
    const float* w_o    = (const float*)d_in[2];
    const float* ln1_g  = (const float*)d_in[3];
    const float* ln1_b  = (const float*)d_in[4];
    const float* ln2_g  = (const float*)d_in[5];
    const float* ln2_b  = (const float*)d_in[6];
    const float* w_fc   = (const float*)d_in[7];
    const float* b_fc   = (const float*)d_in[8];
    const float* w_proj = (const float*)d_in[9];
    const float* b_proj = (const float*)d_in[10];
    float* out = (float*)d_out;

    char* ws = (char*)d_ws;
    const size_t MiB = 1048576;
    unsigned short* ln_buf  = (unsigned short*)ws;
    unsigned short* qkbuf   = (unsigned short*)(ws + 16 * MiB);
    unsigned short* VTbuf   = (unsigned short*)(ws + 48 * MiB);
    unsigned short* wt_attn = (unsigned short*)(ws + 64 * MiB);
    unsigned short* hbuf    = (unsigned short*)(ws + 64 * MiB);
    unsigned short* wt_o    = (unsigned short*)(ws + 126 * MiB);
    unsigned short* pw      = (unsigned short*)(ws + 16 * MiB);   // 2 x 16 MiB
    unsigned short* wt_fc   = (unsigned short*)(ws + 48 * MiB);
    unsigned short* wt_proj = (unsigned short*)(ws + 56 * MiB);
    unsigned short* pp      = (unsigned short*)ws;                // 2 x 16 MiB

    wt_kernel<<<dim3(3072 / 32, 1024 / 32), 256, 0, stream>>>(w_attn, wt_attn, 1024, 3072);
    wt_kernel<<<dim3(1024 / 32, 1024 / 32), 256, 0, stream>>>(w_o, wt_o, 1024, 1024);

    ln_kernel<<<NROWS, 256, 0, stream>>>(x, ln1_g, ln1_b, ln_buf);

    // merged QKV (256x256, 384 blocks): Q(QSCALE)/K -> qkbuf, V -> VTbuf (transposed)
    gemm256<2><<<dim3(NROWS / 256, 3072 / 256), 512, 0, stream>>>(
        ln_buf, wt_attn, nullptr, qkbuf, VTbuf, NROWS, 3072, 1024);

    attn_kernel<<<dim3(8, BATCH * NHEAD), 256, 0, stream>>>(qkbuf, VTbuf, ln_buf);

    // w_o: split-K=2 partials (512 blocks = 2/CU exactly)
    gemm_big<1><<<dim3(NROWS / 256, 1024 / 128, 2), 256, 0, stream>>>(
        ln_buf, wt_o, nullptr, pw, nullptr, NROWS, 1024, 1024, 512);
    // res1 = x + sum(pw) -> d_out ; LN2(res1) -> ln_buf
    reduce_wo_ln2<2><<<NROWS, 256, 0, stream>>>(x, pw, ln2_g, ln2_b, out, ln_buf);

    wt_kernel<<<dim3(4096 / 32, 1024 / 32), 256, 0, stream>>>(w_fc, wt_fc, 1024, 4096);
    wt_kernel<<<dim3(1024 / 32, 4096 / 32), 256, 0, stream>>>(w_proj, wt_proj, 4096, 1024);

    // fc: 256x256 8-wave 2-barrier, gelu+bias fused (512 blocks = exactly 2/CU)
    gemm256<0><<<dim3(NROWS / 256, 4096 / 256), 512, 0, stream>>>(
        ln_buf, wt_fc, b_fc, hbuf, nullptr, NROWS, 4096, 1024);

    // proj: 256x128 BK=64, split-K=2 (2048 each, 512 blocks = 2/CU), then reduce
    gemm_big<1><<<dim3(NROWS / 256, 1024 / 128, 2), 256, 0, stream>>>(
        hbuf, wt_proj, nullptr, pp, nullptr, NROWS, 1024, 4096, 2048);
    reduce_kernel<2><<<NROWS, 256, 0, stream>>>(out, pp, b_proj);
}

// Round 8
// 489.690 us; speedup vs baseline: 1.0305x; 1.0305x over previous
//
#include <hip/hip_runtime.h>
#include <math.h>

#define D_MODEL 1024
#define NHEAD   16
#define HDIM    64
#define SEQ     2048
#define BATCH   4
#define NROWS   (BATCH*SEQ)   // 8192

// Q pre-scale: 1/sqrt(64) * log2(e), so attention can use exp2 directly.
#define QSCALE 0.1803368801111204f

using bf16x8 = __attribute__((ext_vector_type(8))) short;
using bf16x4 = __attribute__((ext_vector_type(4))) short;
using f32x4  = __attribute__((ext_vector_type(4))) float;

__device__ __forceinline__ unsigned short f2bf(float f) {
    unsigned u = __float_as_uint(f);
    u += 0x7fffu + ((u >> 16) & 1u);
    return (unsigned short)(u >> 16);
}
__device__ __forceinline__ float bf2f(unsigned short h) {
    unsigned u = ((unsigned)h) << 16;
    return __uint_as_float(u);
}
// 2^x via v_exp_f32 (gfx950 hw exp is base-2). __exp2f does not exist in HIP.
__device__ __forceinline__ float fast_exp2(float x) {
    return __builtin_amdgcn_exp2f(x);
}

#define ASYNC_COPY16(g, l) \
    __builtin_amdgcn_global_load_lds((__attribute__((address_space(1))) const void*)(g), \
                                     (__attribute__((address_space(3))) void*)(l), 16, 0, 0)

// ---------------- LayerNorm (LN1): one block per row of 1024 --------------------
__global__ __launch_bounds__(256) void ln_kernel(const float* __restrict__ x,
                                                 const float* __restrict__ g,
                                                 const float* __restrict__ b,
                                                 unsigned short* __restrict__ out) {
    const int row = blockIdx.x;
    const int tid = threadIdx.x;
    const float4* x4 = (const float4*)(x + (size_t)row * D_MODEL);
    float4 v = x4[tid];
    float s  = v.x + v.y + v.z + v.w;
    float sq = v.x*v.x + v.y*v.y + v.z*v.z + v.w*v.w;
    #pragma unroll
    for (int off = 32; off >= 1; off >>= 1) {
        s  += __shfl_down(s,  off, 64);
        sq += __shfl_down(sq, off, 64);
    }
    __shared__ float rs[4], rq[4];
    const int wave = tid >> 6;
    if ((tid & 63) == 0) { rs[wave] = s; rq[wave] = sq; }
    __syncthreads();
    const float tot  = rs[0] + rs[1] + rs[2] + rs[3];
    const float totq = rq[0] + rq[1] + rq[2] + rq[3];
    const float mu   = tot * (1.0f / D_MODEL);
    const float var  = totq * (1.0f / D_MODEL) - mu * mu;
    const float rstd = rsqrtf(var + 1e-5f);
    const float4 gv = ((const float4*)g)[tid];
    const float4 bv = ((const float4*)b)[tid];
    unsigned short* o = out + (size_t)row * D_MODEL + tid * 4;
    o[0] = f2bf((v.x - mu) * rstd * gv.x + bv.x);
    o[1] = f2bf((v.y - mu) * rstd * gv.y + bv.y);
    o[2] = f2bf((v.z - mu) * rstd * gv.z + bv.z);
    o[3] = f2bf((v.w - mu) * rstd * gv.w + bv.w);
}

// ------------- Weight transpose+convert: w[K][N] f32 -> wt[N][K] bf16 -----------
__global__ __launch_bounds__(256) void wt_kernel(const float* __restrict__ w,
                                                 unsigned short* __restrict__ wt,
                                                 int K, int N) {
    __shared__ float tile[32][33];
    const int n0 = blockIdx.x * 32, k0 = blockIdx.y * 32;
    const int tx = threadIdx.x & 31, ty = threadIdx.x >> 5;
    #pragma unroll
    for (int j = 0; j < 4; ++j)
        tile[ty + j * 8][tx] = w[(size_t)(k0 + ty + j * 8) * N + n0 + tx];
    __syncthreads();
    #pragma unroll
    for (int j = 0; j < 4; ++j)
        wt[(size_t)(n0 + ty + j * 8) * K + k0 + tx] = f2bf(tile[tx][ty + j * 8]);
}

// ------------- GEMM 256x128, BK=64 (grid: x=m, y=n, [z=split]) ------------------
// 4 waves 2x2: wave covers 128 rows x 64 cols = 8x4 MFMAs x 2 k-halves.
// 48 KiB LDS -> 3 blocks/CU. QKV grid 768 = exactly 3/CU; split-K grids 512 = 2/CU.
// MODE 1: bf16 partial to outp + z*M*N, split-K slices of Kslice (last extends)
// MODE 2: qkv dual-out (n0<1024: xQSCALE -> qk; <2048: -> qk; else V^T store)
template<int MODE>
__global__ __launch_bounds__(256, 2) void gemm_big(const unsigned short* __restrict__ A,
                                                   const unsigned short* __restrict__ Bt,
                                                   const float* __restrict__ bias,
                                                   unsigned short* __restrict__ outp,
                                                   unsigned short* __restrict__ vt_out,
                                                   int M, int N, int K, int Kslice) {
    __shared__ __align__(16) unsigned short As[256 * 64];   // 32 KiB
    __shared__ __align__(16) unsigned short Bs[128 * 64];   // 16 KiB

    const int tid  = threadIdx.x;
    const int lane = tid & 63;
    const int wave = __builtin_amdgcn_readfirstlane(tid >> 6);
    const int quad = lane >> 4, l16 = lane & 15;
    const int wm = wave >> 1, wn = wave & 1;
    const int m0 = blockIdx.x * 256, n0 = blockIdx.y * 128;

    int kbeg = 0, klen = K;
    if (MODE == 1) {
        kbeg = blockIdx.z * Kslice;
        klen = (blockIdx.z == (int)gridDim.z - 1) ? (K - kbeg) : Kslice;
    }

    f32x4 acc[8][4] = {};

    const int rr  = tid >> 3;                 // 0..31
    const int p   = tid & 7;
    const int gch = (p ^ (rr & 7)) * 8;       // swizzled global chunk (elements)

    const unsigned short* Ag[8];
    const unsigned short* Bg[4];
    #pragma unroll
    for (int i = 0; i < 8; ++i)
        Ag[i] = A + (size_t)(m0 + i * 32 + rr) * K + gch + kbeg;
    #pragma unroll
    for (int i = 0; i < 4; ++i)
        Bg[i] = Bt + (size_t)(n0 + i * 32 + rr) * K + gch + kbeg;

    const int pc = (quad ^ (l16 & 7)) * 8;

    for (int kb = 0; kb < klen; kb += 64) {
        #pragma unroll
        for (int i = 0; i < 8; ++i)
            ASYNC_COPY16(Ag[i] + kb, As + i * 2048 + tid * 8);
        #pragma unroll
        for (int i = 0; i < 4; ++i)
            ASYNC_COPY16(Bg[i] + kb, Bs + i * 2048 + tid * 8);
        __syncthreads();

        #pragma unroll
        for (int half = 0; half < 2; ++half) {
            const int off = half ? (pc ^ 32) : pc;
            bf16x8 b[4];
            #pragma unroll
            for (int j = 0; j < 4; ++j)
                b[j] = *(const bf16x8*)&Bs[(wn * 64 + j * 16 + l16) * 64 + off];
            #pragma unroll
            for (int i = 0; i < 8; ++i) {
                bf16x8 a = *(const bf16x8*)&As[(wm * 128 + i * 16 + l16) * 64 + off];
                #pragma unroll
                for (int j = 0; j < 4; ++j)
                    acc[i][j] = __builtin_amdgcn_mfma_f32_16x16x32_bf16(a, b[j], acc[i][j], 0, 0, 0);
            }
        }
        __syncthreads();
    }

    if (MODE == 1) {
        unsigned short* outb = outp + (size_t)blockIdx.z * M * N;
        #pragma unroll
        for (int i = 0; i < 8; ++i)
          #pragma unroll
          for (int j = 0; j < 4; ++j)
            #pragma unroll
            for (int r = 0; r < 4; ++r) {
                const int row = m0 + wm * 128 + i * 16 + quad * 4 + r;
                const int col = n0 + wn * 64 + j * 16 + l16;
                outb[(size_t)row * N + col] = f2bf(acc[i][j][r]);
            }
    } else {
        if (n0 < 2048) {
            const float sc = (n0 < 1024) ? QSCALE : 1.0f;   // block never straddles 1024
            #pragma unroll
            for (int i = 0; i < 8; ++i)
              #pragma unroll
              for (int j = 0; j < 4; ++j)
                #pragma unroll
                for (int r = 0; r < 4; ++r) {
                    const int row = m0 + wm * 128 + i * 16 + quad * 4 + r;
                    const int col = n0 + wn * 64 + j * 16 + l16;
                    outp[(size_t)row * 2048 + col] = f2bf(acc[i][j][r] * sc);
                }
        } else {
            #pragma unroll
            for (int i = 0; i < 8; ++i)
              #pragma unroll
              for (int j = 0; j < 4; ++j) {
                    const int dv  = n0 - 2048 + wn * 64 + j * 16 + l16;
                    const int tok = m0 + wm * 128 + i * 16 + quad * 4;
                    ushort4 pk;
                    pk.x = f2bf(acc[i][j][0]); pk.y = f2bf(acc[i][j][1]);
                    pk.z = f2bf(acc[i][j][2]); pk.w = f2bf(acc[i][j][3]);
                    *(ushort4*)(vt_out + (size_t)dv * NROWS + tok) = pk;
                }
        }
    }
    (void)bias;
}

// ------------- fc GEMM 256x256, BK=64, 8 waves (2x4), 2-barrier -----------------
// Verified (R4/R5/R7): loads/thread 12->8, B staged once per 256 cols, LDS
// 64 KiB -> 2 blocks/CU; fc grid 512 = exactly 2/CU. Bias+gelu epilogue.
__global__ __launch_bounds__(512, 2) void gemm_fc256(const unsigned short* __restrict__ A,
                                                     const unsigned short* __restrict__ Bt,
                                                     const float* __restrict__ bias,
                                                     unsigned short* __restrict__ outp,
                                                     int M, int N, int K) {
    __shared__ __align__(16) unsigned short As[256 * 64];   // 32 KiB
    __shared__ __align__(16) unsigned short Bs[256 * 64];   // 32 KiB

    const int tid  = threadIdx.x;
    const int lane = tid & 63;
    const int wave = __builtin_amdgcn_readfirstlane(tid >> 6);
    const int quad = lane >> 4, l16 = lane & 15;
    const int wm = wave >> 2, wn = wave & 3;
    const int m0 = blockIdx.x * 256, n0 = blockIdx.y * 256;

    f32x4 acc[8][4] = {};

    const int rr  = tid >> 3;                 // 0..63
    const int p   = tid & 7;
    const int gch = (p ^ (rr & 7)) * 8;       // swizzled global chunk (elements)

    const unsigned short* Ag[4];
    const unsigned short* Bg[4];
    #pragma unroll
    for (int i = 0; i < 4; ++i) {
        Ag[i] = A  + (size_t)(m0 + i * 64 + rr) * K + gch;
        Bg[i] = Bt + (size_t)(n0 + i * 64 + rr) * K + gch;
    }

    const int pc = (quad ^ (l16 & 7)) * 8;

    for (int kb = 0; kb < K; kb += 64) {
        #pragma unroll
        for (int i = 0; i < 4; ++i)
            ASYNC_COPY16(Ag[i] + kb, As + i * 4096 + tid * 8);
        #pragma unroll
        for (int i = 0; i < 4; ++i)
            ASYNC_COPY16(Bg[i] + kb, Bs + i * 4096 + tid * 8);
        __syncthreads();

        #pragma unroll
        for (int half = 0; half < 2; ++half) {
            const int off = half ? (pc ^ 32) : pc;
            bf16x8 b[4];
            #pragma unroll
            for (int j = 0; j < 4; ++j)
                b[j] = *(const bf16x8*)&Bs[(wn * 64 + j * 16 + l16) * 64 + off];
            #pragma unroll
            for (int i = 0; i < 8; ++i) {
                bf16x8 a = *(const bf16x8*)&As[(wm * 128 + i * 16 + l16) * 64 + off];
                #pragma unroll
                for (int j = 0; j < 4; ++j)
                    acc[i][j] = __builtin_amdgcn_mfma_f32_16x16x32_bf16(a, b[j], acc[i][j], 0, 0, 0);
            }
        }
        __syncthreads();
    }

    #pragma unroll
    for (int i = 0; i < 8; ++i)
      #pragma unroll
      for (int j = 0; j < 4; ++j)
        #pragma unroll
        for (int r = 0; r < 4; ++r) {
            const int row = m0 + wm * 128 + i * 16 + quad * 4 + r;
            const int col = n0 + wn * 64 + j * 16 + l16;
            float v = acc[i][j][r] + bias[col];
            const float u = 0.7978845608028654f * (v + 0.044715f * v * v * v);
            const float e = __expf(2.0f * u);
            v = 0.5f * v * (2.0f - 2.0f / (e + 1.0f));
            outp[(size_t)row * N + col] = f2bf(v);
        }
}

// ------- fused w_o reduce: res1 = x + p0..p{NP-1} -> out(f32); LN2 -> lnout -----
template<int NP>
__global__ __launch_bounds__(256) void reduce_wo_ln2(const float* __restrict__ x,
                                                     const unsigned short* __restrict__ pw,
                                                     const float* __restrict__ g,
                                                     const float* __restrict__ bb,
                                                     float* __restrict__ out,
                                                     unsigned short* __restrict__ lnout) {
    const int row = blockIdx.x;
    const int tid = threadIdx.x;
    const size_t base = (size_t)row * D_MODEL + tid * 4;
    const size_t stride = (size_t)NROWS * D_MODEL;
    float4 v = *(const float4*)(x + base);
    #pragma unroll
    for (int z = 0; z < NP; ++z) {
        ushort4 a = *(const ushort4*)(pw + z * stride + base);
        v.x += bf2f(a.x); v.y += bf2f(a.y); v.z += bf2f(a.z); v.w += bf2f(a.w);
    }
    *(float4*)(out + base) = v;

    float s  = v.x + v.y + v.z + v.w;
    float sq = v.x*v.x + v.y*v.y + v.z*v.z + v.w*v.w;
    #pragma unroll
    for (int off = 32; off >= 1; off >>= 1) {
        s  += __shfl_down(s,  off, 64);
        sq += __shfl_down(sq, off, 64);
    }
    __shared__ float rs[4], rq[4];
    const int wave = tid >> 6;
    if ((tid & 63) == 0) { rs[wave] = s; rq[wave] = sq; }
    __syncthreads();
    const float tot  = rs[0] + rs[1] + rs[2] + rs[3];
    const float totq = rq[0] + rq[1] + rq[2] + rq[3];
    const float mu   = tot * (1.0f / D_MODEL);
    const float var  = totq * (1.0f / D_MODEL) - mu * mu;
    const float rstd = rsqrtf(var + 1e-5f);
    const float4 gv = ((const float4*)g)[tid];
    const float4 bv = ((const float4*)bb)[tid];
    unsigned short* o = lnout + (size_t)row * D_MODEL + tid * 4;
    o[0] = f2bf((v.x - mu) * rstd * gv.x + bv.x);
    o[1] = f2bf((v.y - mu) * rstd * gv.y + bv.y);
    o[2] = f2bf((v.z - mu) * rstd * gv.z + bv.z);
    o[3] = f2bf((v.w - mu) * rstd * gv.w + bv.w);
}

// ------------- proj split-K reduce: out += bias + p0..p{NP-1} -------------------
template<int NP>
__global__ __launch_bounds__(256) void reduce_kernel(float* __restrict__ out,
                                                     const unsigned short* __restrict__ pp,
                                                     const float* __restrict__ bias) {
    const int row = blockIdx.x;
    const int c0 = threadIdx.x * 4;
    const size_t base = (size_t)row * D_MODEL + c0;
    const size_t stride = (size_t)NROWS * D_MODEL;
    float4 o = *(float4*)(out + base);
    const float4 bs = *(const float4*)(bias + c0);
    o.x += bs.x; o.y += bs.y; o.z += bs.z; o.w += bs.w;
    #pragma unroll
    for (int z = 0; z < NP; ++z) {
        ushort4 a = *(const ushort4*)(pp + z * stride + base);
        o.x += bf2f(a.x); o.y += bf2f(a.y); o.z += bf2f(a.z); o.w += bf2f(a.w);
    }
    *(float4*)(out + base) = o;
}

// ---------------- Flash attention, causal, balanced (paired 128-q tiles) --------
// Double-buffered K/V (prefetch kt+1 at top of kt; vmcnt(0) at tile end only).
// Mid-tile barrier removed (Ps rows intra-wave). exp2 path (Q prescaled by
// log2e at QKV). s_setprio(1) around MFMA clusters (guide m191: attn-positive).
__global__ __launch_bounds__(256) void attn_kernel(const unsigned short* __restrict__ qk,
                                                   const unsigned short* __restrict__ VT,
                                                   unsigned short* __restrict__ y) {
    __shared__ __align__(16) unsigned short Qs[128 * 64];      // 16 KiB
    __shared__ __align__(16) unsigned short Ks[2][64 * 64];    // 16 KiB
    __shared__ __align__(16) unsigned short Vs[2][64 * 64];    // 16 KiB
    __shared__ __align__(16) unsigned short Ones[16 * 64];     //  2 KiB
    __shared__ __align__(16) unsigned short Ps[128 * 68];      // 17 KiB

    const int tid  = threadIdx.x;
    const int lane = tid & 63, w = tid >> 6;
    const int quad = lane >> 4, l16 = lane & 15;
    const int s7   = l16 & 7;
    const int pc0  = (quad ^ s7) * 8;
    const int pc1  = ((quad + 4) ^ s7) * 8;
    const int srow = tid >> 3, sp = tid & 7;
    const int sc   = sp ^ (srow & 7);

    const int pairidx = blockIdx.x;
    const int bh = blockIdx.y;
    const int b = bh >> 4, h = bh & 15;
    const size_t rowbase = (size_t)b * SEQ;
    const unsigned short* Qbase = qk + h * 64;
    const unsigned short* Kbase = qk + 1024 + h * 64;
    const unsigned short* Vbase = VT + (size_t)(h * 64) * NROWS + b * SEQ;

    const unsigned short* Kg0 = Kbase + (rowbase + srow) * 2048 + sc * 8;
    const unsigned short* Kg1 = Kg0 + (size_t)32 * 2048;
    const unsigned short* Vg0 = Vbase + (size_t)srow * NROWS + sc * 8;
    const unsigned short* Vg1 = Vg0 + (size_t)32 * NROWS;

    #pragma unroll
    for (int e = 0; e < 4; ++e) {
        const int off = tid * 4 + e;
        Ones[off] = (off < 64) ? (unsigned short)0x3F80 : (unsigned short)0;
    }

    for (int phase = 0; phase < 2; ++phase) {
        const int Q = phase ? pairidx : (15 - pairidx);
        const int nkt = 2 * Q + 2;
        const int qg0 = Q * 128;

        #pragma unroll
        for (int i = 0; i < 4; ++i)
            ASYNC_COPY16(Qbase + (rowbase + qg0 + i * 32 + srow) * 2048 + sc * 8,
                         (char*)Qs + i * 4096 + tid * 16);
        ASYNC_COPY16(Kg0, (char*)&Ks[0][0] + tid * 16);
        ASYNC_COPY16(Kg1, (char*)&Ks[0][0] + 4096 + tid * 16);
        ASYNC_COPY16(Vg0, (char*)&Vs[0][0] + tid * 16);
        ASYNC_COPY16(Vg1, (char*)&Vs[0][0] + 4096 + tid * 16);
        __syncthreads();

        bf16x8 aq[2][2];
        #pragma unroll
        for (int sub = 0; sub < 2; ++sub) {
            const int qrow = sub * 64 + w * 16 + l16;
            aq[sub][0] = *(const bf16x8*)&Qs[qrow * 64 + pc0];
            aq[sub][1] = *(const bf16x8*)&Qs[qrow * 64 + pc1];
        }

        f32x4 o[2][5] = {};

        for (int kt = 0; kt < nkt; ++kt) {
            const int buf = kt & 1;
            if (kt + 1 < nkt) {
                const size_t koK = (size_t)(kt + 1) * 64 * 2048;
                const size_t koV = (size_t)(kt + 1) * 64;
                ASYNC_COPY16(Kg0 + koK, (char*)&Ks[buf ^ 1][0] + tid * 16);
                ASYNC_COPY16(Kg1 + koK, (char*)&Ks[buf ^ 1][0] + 4096 + tid * 16);
                ASYNC_COPY16(Vg0 + koV, (char*)&Vs[buf ^ 1][0] + tid * 16);
                ASYNC_COPY16(Vg1 + koV, (char*)&Vs[buf ^ 1][0] + 4096 + tid * 16);
            }

            bf16x8 bk[4][2];
            #pragma unroll
            for (int cb = 0; cb < 4; ++cb) {
                const int krow = cb * 16 + l16;
                bk[cb][0] = *(const bf16x8*)&Ks[buf][krow * 64 + pc0];
                bk[cb][1] = *(const bf16x8*)&Ks[buf][krow * 64 + pc1];
            }

            #pragma unroll
            for (int sub = 0; sub < 2; ++sub) {
                if (kt > 2 * Q + sub) continue;
                f32x4 s[4] = {};
                __builtin_amdgcn_s_setprio(1);
                #pragma unroll
                for (int cb = 0; cb < 4; ++cb) {
                    s[cb] = __builtin_amdgcn_mfma_f32_16x16x32_bf16(aq[sub][0], bk[cb][0], s[cb], 0, 0, 0);
                    s[cb] = __builtin_amdgcn_mfma_f32_16x16x32_bf16(aq[sub][1], bk[cb][1], s[cb], 0, 0, 0);
                }
                __builtin_amdgcn_s_setprio(0);
                const int prow0 = sub * 64 + w * 16 + quad * 4;
                if (kt == 2 * Q + sub) {
                    const int qg = qg0 + prow0;
                    const int kg = kt * 64 + l16;
                    #pragma unroll
                    for (int cb = 0; cb < 4; ++cb)
                        #pragma unroll
                        for (int r = 0; r < 4; ++r) {
                            const float e = fast_exp2(s[cb][r]);
                            const float pv = (kg + cb * 16 > qg + r) ? 0.0f : e;
                            Ps[(prow0 + r) * 68 + cb * 16 + l16] = f2bf(pv);
                        }
                } else {
                    #pragma unroll
                    for (int cb = 0; cb < 4; ++cb)
                        #pragma unroll
                        for (int r = 0; r < 4; ++r)
                            Ps[(prow0 + r) * 68 + cb * 16 + l16] = f2bf(fast_exp2(s[cb][r]));
                }
            }
            asm volatile("s_waitcnt lgkmcnt(0)" ::: "memory");

            bf16x8 bv[5][2];
            #pragma unroll
            for (int db = 0; db < 4; ++db) {
                const int vrow = db * 16 + l16;
                bv[db][0] = *(const bf16x8*)&Vs[buf][vrow * 64 + pc0];
                bv[db][1] = *(const bf16x8*)&Vs[buf][vrow * 64 + pc1];
            }
            bv[4][0] = *(const bf16x8*)&Ones[l16 * 64 + pc0];
            bv[4][1] = *(const bf16x8*)&Ones[l16 * 64 + pc1];

            #pragma unroll
            for (int sub = 0; sub < 2; ++sub) {
                if (kt > 2 * Q + sub) continue;
                const unsigned short* pb = &Ps[(sub * 64 + w * 16 + l16) * 68];
                bf16x8 ap0, ap1;
                *(bf16x4*)&ap0       = *(const bf16x4*)(pb + quad * 8);
                *((bf16x4*)&ap0 + 1) = *(const bf16x4*)(pb + quad * 8 + 4);
                *(bf16x4*)&ap1       = *(const bf16x4*)(pb + 32 + quad * 8);
                *((bf16x4*)&ap1 + 1) = *(const bf16x4*)(pb + 32 + quad * 8 + 4);
                __builtin_amdgcn_s_setprio(1);
                #pragma unroll
                for (int db = 0; db < 5; ++db) {
                    o[sub][db] = __builtin_amdgcn_mfma_f32_16x16x32_bf16(ap0, bv[db][0], o[sub][db], 0, 0, 0);
                    o[sub][db] = __builtin_amdgcn_mfma_f32_16x16x32_bf16(ap1, bv[db][1], o[sub][db], 0, 0, 0);
                }
                __builtin_amdgcn_s_setprio(0);
            }
            asm volatile("s_waitcnt vmcnt(0)" ::: "memory");
            __syncthreads();
        }

        #pragma unroll
        for (int sub = 0; sub < 2; ++sub)
            #pragma unroll
            for (int r = 0; r < 4; ++r) {
                const float lsum = __shfl(o[sub][4][r], lane & 48);
                const float rinv = 1.0f / lsum;
                const int trow = qg0 + sub * 64 + w * 16 + quad * 4 + r;
                unsigned short* yp = y + (rowbase + trow) * (size_t)D_MODEL + h * 64 + l16;
                #pragma unroll
                for (int db = 0; db < 4; ++db)
                    yp[db * 16] = f2bf(o[sub][db][r] * rinv);
            }
    }
}

extern "C" void kernel_launch(void* const* d_in, const int* in_sizes, int n_in,
                              void* d_out, int out_size, void* d_ws, size_t ws_size,
                              hipStream_t stream) {
    (void)in_sizes; (void)n_in; (void)out_size; (void)ws_size;
    const float* x      = (const float*)d_in[0];
    const float* w_attn = (const float*)d_in[1];
    const float* w_o    = (const float*)d_in[2];
    const float* ln1_g  = (const float*)d_in[3];
    const float* ln1_b  = (const float*)d_in[4];
    const float* ln2_g  = (const float*)d_in[5];
    const float* ln2_b  = (const float*)d_in[6];
    const float* w_fc   = (const float*)d_in[7];
    const float* b_fc   = (const float*)d_in[8];
    const float* w_proj = (const float*)d_in[9];
    const float* b_proj = (const float*)d_in[10];
    float* out = (float*)d_out;

    char* ws = (char*)d_ws;
    const size_t MiB = 1048576;
    unsigned short* ln_buf  = (unsigned short*)ws;
    unsigned short* qkbuf   = (unsigned short*)(ws + 16 * MiB);
    unsigned short* VTbuf   = (unsigned short*)(ws + 48 * MiB);
    unsigned short* wt_attn = (unsigned short*)(ws + 64 * MiB);
    unsigned short* hbuf    = (unsigned short*)(ws + 64 * MiB);
    unsigned short* wt_o    = (unsigned short*)(ws + 126 * MiB);
    unsigned short* pw      = (unsigned short*)(ws + 16 * MiB);   // 2 x 16 MiB
    unsigned short* wt_fc   = (unsigned short*)(ws + 48 * MiB);
    unsigned short* wt_proj = (unsigned short*)(ws + 56 * MiB);
    unsigned short* pp      = (unsigned short*)ws;                // 2 x 16 MiB

    wt_kernel<<<dim3(3072 / 32, 1024 / 32), 256, 0, stream>>>(w_attn, wt_attn, 1024, 3072);
    wt_kernel<<<dim3(1024 / 32, 1024 / 32), 256, 0, stream>>>(w_o, wt_o, 1024, 1024);

    ln_kernel<<<NROWS, 256, 0, stream>>>(x, ln1_g, ln1_b, ln_buf);

    // merged QKV (256x128 BK=64, 768 blocks = exactly 3/CU):
    // Q(scaled by QSCALE)/K -> qkbuf, V -> VTbuf (transposed)
    gemm_big<2><<<dim3(NROWS / 256, 3072 / 128), 256, 0, stream>>>(
        ln_buf, wt_attn, nullptr, qkbuf, VTbuf, NROWS, 3072, 1024, 0);

    attn_kernel<<<dim3(8, BATCH * NHEAD), 256, 0, stream>>>(qkbuf, VTbuf, ln_buf);

    // w_o: split-K=2 partials (512 blocks = 2/CU, fits at 3/CU capacity)
    gemm_big<1><<<dim3(NROWS / 256, 1024 / 128, 2), 256, 0, stream>>>(
        ln_buf, wt_o, nullptr, pw, nullptr, NROWS, 1024, 1024, 512);
    // res1 = x + sum(pw) -> d_out ; LN2(res1) -> ln_buf
    reduce_wo_ln2<2><<<NROWS, 256, 0, stream>>>(x, pw, ln2_g, ln2_b, out, ln_buf);

    wt_kernel<<<dim3(4096 / 32, 1024 / 32), 256, 0, stream>>>(w_fc, wt_fc, 1024, 4096);
    wt_kernel<<<dim3(1024 / 32, 4096 / 32), 256, 0, stream>>>(w_proj, wt_proj, 4096, 1024);

    // fc: 256x256 8-wave 2-barrier, gelu+bias fused (512 blocks = exactly 2/CU)
    gemm_fc256<<<dim3(NROWS / 256, 4096 / 256), 512, 0, stream>>>(
        ln_buf, wt_fc, b_fc, hbuf, NROWS, 4096, 1024);

    // proj: 256x128 BK=64, split-K=2 (2048 each, 512 blocks = 2/CU), then reduce
    gemm_big<1><<<dim3(NROWS / 256, 1024 / 128, 2), 256, 0, stream>>>(
        hbuf, wt_proj, nullptr, pp, nullptr, NROWS, 1024, 4096, 2048);
    reduce_kernel<2><<<NROWS, 256, 0, stream>>>(out, pp, b_proj);
}

// Round 9
// 472.371 us; speedup vs baseline: 1.0683x; 1.0367x over previous
//
#include <hip/hip_runtime.h>
#include <math.h>

#define D_MODEL 1024
#define NHEAD   16
#define HDIM    64
#define SEQ     2048
#define BATCH   4
#define NROWS   (BATCH*SEQ)   // 8192

// Q pre-scale: 1/sqrt(64) * log2(e), so attention can use exp2 directly.
#define QSCALE 0.1803368801111204f

using bf16x8 = __attribute__((ext_vector_type(8))) short;
using bf16x4 = __attribute__((ext_vector_type(4))) short;
using f32x4  = __attribute__((ext_vector_type(4))) float;

__device__ __forceinline__ unsigned short f2bf(float f) {
    unsigned u = __float_as_uint(f);
    u += 0x7fffu + ((u >> 16) & 1u);
    return (unsigned short)(u >> 16);
}
__device__ __forceinline__ float bf2f(unsigned short h) {
    unsigned u = ((unsigned)h) << 16;
    return __uint_as_float(u);
}
// 2^x via v_exp_f32 (gfx950 hw exp is base-2). __exp2f does not exist in HIP.
__device__ __forceinline__ float fast_exp2(float x) {
    return __builtin_amdgcn_exp2f(x);
}

#define ASYNC_COPY16(g, l) \
    __builtin_amdgcn_global_load_lds((__attribute__((address_space(1))) const void*)(g), \
                                     (__attribute__((address_space(3))) void*)(l), 16, 0, 0)

// ---------------- LayerNorm (LN1): one block per row of 1024 --------------------
__global__ __launch_bounds__(256) void ln_kernel(const float* __restrict__ x,
                                                 const float* __restrict__ g,
                                                 const float* __restrict__ b,
                                                 unsigned short* __restrict__ out) {
    const int row = blockIdx.x;
    const int tid = threadIdx.x;
    const float4* x4 = (const float4*)(x + (size_t)row * D_MODEL);
    float4 v = x4[tid];
    float s  = v.x + v.y + v.z + v.w;
    float sq = v.x*v.x + v.y*v.y + v.z*v.z + v.w*v.w;
    #pragma unroll
    for (int off = 32; off >= 1; off >>= 1) {
        s  += __shfl_down(s,  off, 64);
        sq += __shfl_down(sq, off, 64);
    }
    __shared__ float rs[4], rq[4];
    const int wave = tid >> 6;
    if ((tid & 63) == 0) { rs[wave] = s; rq[wave] = sq; }
    __syncthreads();
    const float tot  = rs[0] + rs[1] + rs[2] + rs[3];
    const float totq = rq[0] + rq[1] + rq[2] + rq[3];
    const float mu   = tot * (1.0f / D_MODEL);
    const float var  = totq * (1.0f / D_MODEL) - mu * mu;
    const float rstd = rsqrtf(var + 1e-5f);
    const float4 gv = ((const float4*)g)[tid];
    const float4 bv = ((const float4*)b)[tid];
    unsigned short* o = out + (size_t)row * D_MODEL + tid * 4;
    o[0] = f2bf((v.x - mu) * rstd * gv.x + bv.x);
    o[1] = f2bf((v.y - mu) * rstd * gv.y + bv.y);
    o[2] = f2bf((v.z - mu) * rstd * gv.z + bv.z);
    o[3] = f2bf((v.w - mu) * rstd * gv.w + bv.w);
}

// ------------- Weight transpose+convert: w[K][N] f32 -> wt[N][K] bf16 -----------
__global__ __launch_bounds__(256) void wt_kernel(const float* __restrict__ w,
                                                 unsigned short* __restrict__ wt,
                                                 int K, int N) {
    __shared__ float tile[32][33];
    const int n0 = blockIdx.x * 32, k0 = blockIdx.y * 32;
    const int tx = threadIdx.x & 31, ty = threadIdx.x >> 5;
    #pragma unroll
    for (int j = 0; j < 4; ++j)
        tile[ty + j * 8][tx] = w[(size_t)(k0 + ty + j * 8) * N + n0 + tx];
    __syncthreads();
    #pragma unroll
    for (int j = 0; j < 4; ++j)
        wt[(size_t)(n0 + ty + j * 8) * K + k0 + tx] = f2bf(tile[tx][ty + j * 8]);
}

// ------------- GEMM 256x128, BK=64 (grid: x=m, y=n, [z=split]) ------------------
// 4 waves 2x2: wave covers 128 rows x 64 cols = 8x4 MFMAs x 2 k-halves.
// 48 KiB LDS -> 3 blocks/CU max; many small desynced blocks give the implicit
// cross-block overlap that beats bigger tiles / explicit pipelining here (R4/R5
// A/B: fc as gemm_big beat fc256 by ~10 us; R7/R8: qkv256 tail cost ~15 us).
// MODE 0: bias+gelu bf16 out (fc)
// MODE 1: bf16 partial to outp + z*M*N, split-K slices of Kslice (last extends)
// MODE 2: qkv dual-out (n0<1024: xQSCALE -> qk; <2048: -> qk; else V^T store)
template<int MODE>
__global__ __launch_bounds__(256, 2) void gemm_big(const unsigned short* __restrict__ A,
                                                   const unsigned short* __restrict__ Bt,
                                                   const float* __restrict__ bias,
                                                   unsigned short* __restrict__ outp,
                                                   unsigned short* __restrict__ vt_out,
                                                   int M, int N, int K, int Kslice) {
    __shared__ __align__(16) unsigned short As[256 * 64];   // 32 KiB
    __shared__ __align__(16) unsigned short Bs[128 * 64];   // 16 KiB

    const int tid  = threadIdx.x;
    const int lane = tid & 63;
    const int wave = __builtin_amdgcn_readfirstlane(tid >> 6);
    const int quad = lane >> 4, l16 = lane & 15;
    const int wm = wave >> 1, wn = wave & 1;
    const int m0 = blockIdx.x * 256, n0 = blockIdx.y * 128;

    int kbeg = 0, klen = K;
    if (MODE == 1) {
        kbeg = blockIdx.z * Kslice;
        klen = (blockIdx.z == (int)gridDim.z - 1) ? (K - kbeg) : Kslice;
    }

    f32x4 acc[8][4] = {};

    const int rr  = tid >> 3;                 // 0..31
    const int p   = tid & 7;
    const int gch = (p ^ (rr & 7)) * 8;       // swizzled global chunk (elements)

    const unsigned short* Ag[8];
    const unsigned short* Bg[4];
    #pragma unroll
    for (int i = 0; i < 8; ++i)
        Ag[i] = A + (size_t)(m0 + i * 32 + rr) * K + gch + kbeg;
    #pragma unroll
    for (int i = 0; i < 4; ++i)
        Bg[i] = Bt + (size_t)(n0 + i * 32 + rr) * K + gch + kbeg;

    const int pc = (quad ^ (l16 & 7)) * 8;

    for (int kb = 0; kb < klen; kb += 64) {
        #pragma unroll
        for (int i = 0; i < 8; ++i)
            ASYNC_COPY16(Ag[i] + kb, As + i * 2048 + tid * 8);
        #pragma unroll
        for (int i = 0; i < 4; ++i)
            ASYNC_COPY16(Bg[i] + kb, Bs + i * 2048 + tid * 8);
        __syncthreads();

        #pragma unroll
        for (int half = 0; half < 2; ++half) {
            const int off = half ? (pc ^ 32) : pc;
            bf16x8 b[4];
            #pragma unroll
            for (int j = 0; j < 4; ++j)
                b[j] = *(const bf16x8*)&Bs[(wn * 64 + j * 16 + l16) * 64 + off];
            #pragma unroll
            for (int i = 0; i < 8; ++i) {
                bf16x8 a = *(const bf16x8*)&As[(wm * 128 + i * 16 + l16) * 64 + off];
                #pragma unroll
                for (int j = 0; j < 4; ++j)
                    acc[i][j] = __builtin_amdgcn_mfma_f32_16x16x32_bf16(a, b[j], acc[i][j], 0, 0, 0);
            }
        }
        __syncthreads();
    }

    if (MODE == 0) {
        #pragma unroll
        for (int i = 0; i < 8; ++i)
          #pragma unroll
          for (int j = 0; j < 4; ++j)
            #pragma unroll
            for (int r = 0; r < 4; ++r) {
                const int row = m0 + wm * 128 + i * 16 + quad * 4 + r;
                const int col = n0 + wn * 64 + j * 16 + l16;
                float v = acc[i][j][r] + bias[col];
                const float u = 0.7978845608028654f * (v + 0.044715f * v * v * v);
                const float e = __expf(2.0f * u);
                v = 0.5f * v * (2.0f - 2.0f / (e + 1.0f));
                outp[(size_t)row * N + col] = f2bf(v);
            }
    } else if (MODE == 1) {
        unsigned short* outb = outp + (size_t)blockIdx.z * M * N;
        #pragma unroll
        for (int i = 0; i < 8; ++i)
          #pragma unroll
          for (int j = 0; j < 4; ++j)
            #pragma unroll
            for (int r = 0; r < 4; ++r) {
                const int row = m0 + wm * 128 + i * 16 + quad * 4 + r;
                const int col = n0 + wn * 64 + j * 16 + l16;
                outb[(size_t)row * N + col] = f2bf(acc[i][j][r]);
            }
    } else {
        if (n0 < 2048) {
            const float sc = (n0 < 1024) ? QSCALE : 1.0f;   // block never straddles 1024
            #pragma unroll
            for (int i = 0; i < 8; ++i)
              #pragma unroll
              for (int j = 0; j < 4; ++j)
                #pragma unroll
                for (int r = 0; r < 4; ++r) {
                    const int row = m0 + wm * 128 + i * 16 + quad * 4 + r;
                    const int col = n0 + wn * 64 + j * 16 + l16;
                    outp[(size_t)row * 2048 + col] = f2bf(acc[i][j][r] * sc);
                }
        } else {
            #pragma unroll
            for (int i = 0; i < 8; ++i)
              #pragma unroll
              for (int j = 0; j < 4; ++j) {
                    const int dv  = n0 - 2048 + wn * 64 + j * 16 + l16;
                    const int tok = m0 + wm * 128 + i * 16 + quad * 4;
                    ushort4 pk;
                    pk.x = f2bf(acc[i][j][0]); pk.y = f2bf(acc[i][j][1]);
                    pk.z = f2bf(acc[i][j][2]); pk.w = f2bf(acc[i][j][3]);
                    *(ushort4*)(vt_out + (size_t)dv * NROWS + tok) = pk;
                }
        }
    }
}

// ------- fused w_o reduce: res1 = x + p0..p{NP-1} -> out(f32); LN2 -> lnout -----
template<int NP>
__global__ __launch_bounds__(256) void reduce_wo_ln2(const float* __restrict__ x,
                                                     const unsigned short* __restrict__ pw,
                                                     const float* __restrict__ g,
                                                     const float* __restrict__ bb,
                                                     float* __restrict__ out,
                                                     unsigned short* __restrict__ lnout) {
    const int row = blockIdx.x;
    const int tid = threadIdx.x;
    const size_t base = (size_t)row * D_MODEL + tid * 4;
    const size_t stride = (size_t)NROWS * D_MODEL;
    float4 v = *(const float4*)(x + base);
    #pragma unroll
    for (int z = 0; z < NP; ++z) {
        ushort4 a = *(const ushort4*)(pw + z * stride + base);
        v.x += bf2f(a.x); v.y += bf2f(a.y); v.z += bf2f(a.z); v.w += bf2f(a.w);
    }
    *(float4*)(out + base) = v;

    float s  = v.x + v.y + v.z + v.w;
    float sq = v.x*v.x + v.y*v.y + v.z*v.z + v.w*v.w;
    #pragma unroll
    for (int off = 32; off >= 1; off >>= 1) {
        s  += __shfl_down(s,  off, 64);
        sq += __shfl_down(sq, off, 64);
    }
    __shared__ float rs[4], rq[4];
    const int wave = tid >> 6;
    if ((tid & 63) == 0) { rs[wave] = s; rq[wave] = sq; }
    __syncthreads();
    const float tot  = rs[0] + rs[1] + rs[2] + rs[3];
    const float totq = rq[0] + rq[1] + rq[2] + rq[3];
    const float mu   = tot * (1.0f / D_MODEL);
    const float var  = totq * (1.0f / D_MODEL) - mu * mu;
    const float rstd = rsqrtf(var + 1e-5f);
    const float4 gv = ((const float4*)g)[tid];
    const float4 bv = ((const float4*)bb)[tid];
    unsigned short* o = lnout + (size_t)row * D_MODEL + tid * 4;
    o[0] = f2bf((v.x - mu) * rstd * gv.x + bv.x);
    o[1] = f2bf((v.y - mu) * rstd * gv.y + bv.y);
    o[2] = f2bf((v.z - mu) * rstd * gv.z + bv.z);
    o[3] = f2bf((v.w - mu) * rstd * gv.w + bv.w);
}

// ------------- proj split-K reduce: out += bias + p0..p{NP-1} -------------------
template<int NP>
__global__ __launch_bounds__(256) void reduce_kernel(float* __restrict__ out,
                                                     const unsigned short* __restrict__ pp,
                                                     const float* __restrict__ bias) {
    const int row = blockIdx.x;
    const int c0 = threadIdx.x * 4;
    const size_t base = (size_t)row * D_MODEL + c0;
    const size_t stride = (size_t)NROWS * D_MODEL;
    float4 o = *(float4*)(out + base);
    const float4 bs = *(const float4*)(bias + c0);
    o.x += bs.x; o.y += bs.y; o.z += bs.z; o.w += bs.w;
    #pragma unroll
    for (int z = 0; z < NP; ++z) {
        ushort4 a = *(const ushort4*)(pp + z * stride + base);
        o.x += bf2f(a.x); o.y += bf2f(a.y); o.z += bf2f(a.z); o.w += bf2f(a.w);
    }
    *(float4*)(out + base) = o;
}

// ---------------- Flash attention, causal, balanced (paired 128-q tiles) --------
// Double-buffered K/V (prefetch kt+1 at top of kt; vmcnt(0) at tile end only).
// Mid-tile barrier removed (Ps rows intra-wave). exp2 path (Q prescaled by
// log2e at QKV). s_setprio(1) around MFMA clusters (guide m191: attn-positive).
__global__ __launch_bounds__(256) void attn_kernel(const unsigned short* __restrict__ qk,
                                                   const unsigned short* __restrict__ VT,
                                                   unsigned short* __restrict__ y) {
    __shared__ __align__(16) unsigned short Qs[128 * 64];      // 16 KiB
    __shared__ __align__(16) unsigned short Ks[2][64 * 64];    // 16 KiB
    __shared__ __align__(16) unsigned short Vs[2][64 * 64];    // 16 KiB
    __shared__ __align__(16) unsigned short Ones[16 * 64];     //  2 KiB
    __shared__ __align__(16) unsigned short Ps[128 * 68];      // 17 KiB

    const int tid  = threadIdx.x;
    const int lane = tid & 63, w = tid >> 6;
    const int quad = lane >> 4, l16 = lane & 15;
    const int s7   = l16 & 7;
    const int pc0  = (quad ^ s7) * 8;
    const int pc1  = ((quad + 4) ^ s7) * 8;
    const int srow = tid >> 3, sp = tid & 7;
    const int sc   = sp ^ (srow & 7);

    const int pairidx = blockIdx.x;
    const int bh = blockIdx.y;
    const int b = bh >> 4, h = bh & 15;
    const size_t rowbase = (size_t)b * SEQ;
    const unsigned short* Qbase = qk + h * 64;
    const unsigned short* Kbase = qk + 1024 + h * 64;
    const unsigned short* Vbase = VT + (size_t)(h * 64) * NROWS + b * SEQ;

    const unsigned short* Kg0 = Kbase + (rowbase + srow) * 2048 + sc * 8;
    const unsigned short* Kg1 = Kg0 + (size_t)32 * 2048;
    const unsigned short* Vg0 = Vbase + (size_t)srow * NROWS + sc * 8;
    const unsigned short* Vg1 = Vg0 + (size_t)32 * NROWS;

    #pragma unroll
    for (int e = 0; e < 4; ++e) {
        const int off = tid * 4 + e;
        Ones[off] = (off < 64) ? (unsigned short)0x3F80 : (unsigned short)0;
    }

    for (int phase = 0; phase < 2; ++phase) {
        const int Q = phase ? pairidx : (15 - pairidx);
        const int nkt = 2 * Q + 2;
        const int qg0 = Q * 128;

        #pragma unroll
        for (int i = 0; i < 4; ++i)
            ASYNC_COPY16(Qbase + (rowbase + qg0 + i * 32 + srow) * 2048 + sc * 8,
                         (char*)Qs + i * 4096 + tid * 16);
        ASYNC_COPY16(Kg0, (char*)&Ks[0][0] + tid * 16);
        ASYNC_COPY16(Kg1, (char*)&Ks[0][0] + 4096 + tid * 16);
        ASYNC_COPY16(Vg0, (char*)&Vs[0][0] + tid * 16);
        ASYNC_COPY16(Vg1, (char*)&Vs[0][0] + 4096 + tid * 16);
        __syncthreads();

        bf16x8 aq[2][2];
        #pragma unroll
        for (int sub = 0; sub < 2; ++sub) {
            const int qrow = sub * 64 + w * 16 + l16;
            aq[sub][0] = *(const bf16x8*)&Qs[qrow * 64 + pc0];
            aq[sub][1] = *(const bf16x8*)&Qs[qrow * 64 + pc1];
        }

        f32x4 o[2][5] = {};

        for (int kt = 0; kt < nkt; ++kt) {
            const int buf = kt & 1;
            if (kt + 1 < nkt) {
                const size_t koK = (size_t)(kt + 1) * 64 * 2048;
                const size_t koV = (size_t)(kt + 1) * 64;
                ASYNC_COPY16(Kg0 + koK, (char*)&Ks[buf ^ 1][0] + tid * 16);
                ASYNC_COPY16(Kg1 + koK, (char*)&Ks[buf ^ 1][0] + 4096 + tid * 16);
                ASYNC_COPY16(Vg0 + koV, (char*)&Vs[buf ^ 1][0] + tid * 16);
                ASYNC_COPY16(Vg1 + koV, (char*)&Vs[buf ^ 1][0] + 4096 + tid * 16);
            }

            bf16x8 bk[4][2];
            #pragma unroll
            for (int cb = 0; cb < 4; ++cb) {
                const int krow = cb * 16 + l16;
                bk[cb][0] = *(const bf16x8*)&Ks[buf][krow * 64 + pc0];
                bk[cb][1] = *(const bf16x8*)&Ks[buf][krow * 64 + pc1];
            }

            #pragma unroll
            for (int sub = 0; sub < 2; ++sub) {
                if (kt > 2 * Q + sub) continue;
                f32x4 s[4] = {};
                __builtin_amdgcn_s_setprio(1);
                #pragma unroll
                for (int cb = 0; cb < 4; ++cb) {
                    s[cb] = __builtin_amdgcn_mfma_f32_16x16x32_bf16(aq[sub][0], bk[cb][0], s[cb], 0, 0, 0);
                    s[cb] = __builtin_amdgcn_mfma_f32_16x16x32_bf16(aq[sub][1], bk[cb][1], s[cb], 0, 0, 0);
                }
                __builtin_amdgcn_s_setprio(0);
                const int prow0 = sub * 64 + w * 16 + quad * 4;
                if (kt == 2 * Q + sub) {
                    const int qg = qg0 + prow0;
                    const int kg = kt * 64 + l16;
                    #pragma unroll
                    for (int cb = 0; cb < 4; ++cb)
                        #pragma unroll
                        for (int r = 0; r < 4; ++r) {
                            const float e = fast_exp2(s[cb][r]);
                            const float pv = (kg + cb * 16 > qg + r) ? 0.0f : e;
                            Ps[(prow0 + r) * 68 + cb * 16 + l16] = f2bf(pv);
                        }
                } else {
                    #pragma unroll
                    for (int cb = 0; cb < 4; ++cb)
                        #pragma unroll
                        for (int r = 0; r < 4; ++r)
                            Ps[(prow0 + r) * 68 + cb * 16 + l16] = f2bf(fast_exp2(s[cb][r]));
                }
            }
            asm volatile("s_waitcnt lgkmcnt(0)" ::: "memory");

            bf16x8 bv[5][2];
            #pragma unroll
            for (int db = 0; db < 4; ++db) {
                const int vrow = db * 16 + l16;
                bv[db][0] = *(const bf16x8*)&Vs[buf][vrow * 64 + pc0];
                bv[db][1] = *(const bf16x8*)&Vs[buf][vrow * 64 + pc1];
            }
            bv[4][0] = *(const bf16x8*)&Ones[l16 * 64 + pc0];
            bv[4][1] = *(const bf16x8*)&Ones[l16 * 64 + pc1];

            #pragma unroll
            for (int sub = 0; sub < 2; ++sub) {
                if (kt > 2 * Q + sub) continue;
                const unsigned short* pb = &Ps[(sub * 64 + w * 16 + l16) * 68];
                bf16x8 ap0, ap1;
                *(bf16x4*)&ap0       = *(const bf16x4*)(pb + quad * 8);
                *((bf16x4*)&ap0 + 1) = *(const bf16x4*)(pb + quad * 8 + 4);
                *(bf16x4*)&ap1       = *(const bf16x4*)(pb + 32 + quad * 8);
                *((bf16x4*)&ap1 + 1) = *(const bf16x4*)(pb + 32 + quad * 8 + 4);
                __builtin_amdgcn_s_setprio(1);
                #pragma unroll
                for (int db = 0; db < 5; ++db) {
                    o[sub][db] = __builtin_amdgcn_mfma_f32_16x16x32_bf16(ap0, bv[db][0], o[sub][db], 0, 0, 0);
                    o[sub][db] = __builtin_amdgcn_mfma_f32_16x16x32_bf16(ap1, bv[db][1], o[sub][db], 0, 0, 0);
                }
                __builtin_amdgcn_s_setprio(0);
            }
            asm volatile("s_waitcnt vmcnt(0)" ::: "memory");
            __syncthreads();
        }

        #pragma unroll
        for (int sub = 0; sub < 2; ++sub)
            #pragma unroll
            for (int r = 0; r < 4; ++r) {
                const float lsum = __shfl(o[sub][4][r], lane & 48);
                const float rinv = 1.0f / lsum;
                const int trow = qg0 + sub * 64 + w * 16 + quad * 4 + r;
                unsigned short* yp = y + (rowbase + trow) * (size_t)D_MODEL + h * 64 + l16;
                #pragma unroll
                for (int db = 0; db < 4; ++db)
                    yp[db * 16] = f2bf(o[sub][db][r] * rinv);
            }
    }
}

extern "C" void kernel_launch(void* const* d_in, const int* in_sizes, int n_in,
                              void* d_out, int out_size, void* d_ws, size_t ws_size,
                              hipStream_t stream) {
    (void)in_sizes; (void)n_in; (void)out_size; (void)ws_size;
    const float* x      = (const float*)d_in[0];
    const float* w_attn = (const float*)d_in[1];
    const float* w_o    = (const float*)d_in[2];
    const float* ln1_g  = (const float*)d_in[3];
    const float* ln1_b  = (const float*)d_in[4];
    const float* ln2_g  = (const float*)d_in[5];
    const float* ln2_b  = (const float*)d_in[6];
    const float* w_fc   = (const float*)d_in[7];
    const float* b_fc   = (const float*)d_in[8];
    const float* w_proj = (const float*)d_in[9];
    const float* b_proj = (const float*)d_in[10];
    float* out = (float*)d_out;

    char* ws = (char*)d_ws;
    const size_t MiB = 1048576;
    unsigned short* ln_buf  = (unsigned short*)ws;
    unsigned short* qkbuf   = (unsigned short*)(ws + 16 * MiB);
    unsigned short* VTbuf   = (unsigned short*)(ws + 48 * MiB);
    unsigned short* wt_attn = (unsigned short*)(ws + 64 * MiB);
    unsigned short* hbuf    = (unsigned short*)(ws + 64 * MiB);
    unsigned short* wt_o    = (unsigned short*)(ws + 126 * MiB);
    unsigned short* pw      = (unsigned short*)(ws + 16 * MiB);   // 2 x 16 MiB
    unsigned short* wt_fc   = (unsigned short*)(ws + 48 * MiB);
    unsigned short* wt_proj = (unsigned short*)(ws + 56 * MiB);
    unsigned short* pp      = (unsigned short*)ws;                // 2 x 16 MiB

    wt_kernel<<<dim3(3072 / 32, 1024 / 32), 256, 0, stream>>>(w_attn, wt_attn, 1024, 3072);
    wt_kernel<<<dim3(1024 / 32, 1024 / 32), 256, 0, stream>>>(w_o, wt_o, 1024, 1024);

    ln_kernel<<<NROWS, 256, 0, stream>>>(x, ln1_g, ln1_b, ln_buf);

    // merged QKV (256x128 BK=64, 768 blocks = exactly 3/CU):
    // Q(scaled by QSCALE)/K -> qkbuf, V -> VTbuf (transposed)
    gemm_big<2><<<dim3(NROWS / 256, 3072 / 128), 256, 0, stream>>>(
        ln_buf, wt_attn, nullptr, qkbuf, VTbuf, NROWS, 3072, 1024, 0);

    attn_kernel<<<dim3(8, BATCH * NHEAD), 256, 0, stream>>>(qkbuf, VTbuf, ln_buf);

    // w_o: split-K=2 partials (512 blocks = 2/CU)
    gemm_big<1><<<dim3(NROWS / 256, 1024 / 128, 2), 256, 0, stream>>>(
        ln_buf, wt_o, nullptr, pw, nullptr, NROWS, 1024, 1024, 512);
    // res1 = x + sum(pw) -> d_out ; LN2(res1) -> ln_buf
    reduce_wo_ln2<2><<<NROWS, 256, 0, stream>>>(x, pw, ln2_g, ln2_b, out, ln_buf);

    wt_kernel<<<dim3(4096 / 32, 1024 / 32), 256, 0, stream>>>(w_fc, wt_fc, 1024, 4096);
    wt_kernel<<<dim3(1024 / 32, 4096 / 32), 256, 0, stream>>>(w_proj, wt_proj, 4096, 1024);

    // fc: 256x128 BK=64, gelu+bias fused (1024 blocks, 3/CU residency)
    gemm_big<0><<<dim3(NROWS / 256, 4096 / 128), 256, 0, stream>>>(
        ln_buf, wt_fc, b_fc, hbuf, nullptr, NROWS, 4096, 1024, 0);

    // proj: 256x128 BK=64, split-K=2 (2048 each, 512 blocks = 2/CU), then reduce
    gemm_big<1><<<dim3(NROWS / 256, 1024 / 128, 2), 256, 0, stream>>>(
        hbuf, wt_proj, nullptr, pp, nullptr, NROWS, 1024, 4096, 2048);
    reduce_kernel<2><<<NROWS, 256, 0, stream>>>(out, pp, b_proj);
}